// Round 1
// baseline (2517.504 us; speedup 1.0000x reference)
//
#include <hip/hip_runtime.h>
#include <cmath>

// Problem constants: B=32, T=512, S=1024, D=1024
#define BATCH 32
#define TLEN  512
#define SLEN  1024
#define DIM   1024

#define BM 64
#define BN 64
#define BK 16

// Generic fp32 tiled GEMM.
// C[m,n] = sum_k A[m,k] * B[n,k]   (B_IS_NT=true,  B is [N,K] row-major)
// C[m,n] = sum_k A[m,k] * B[k,n]   (B_IS_NT=false, B is [K,N] row-major)
// Optional tanh epilogue. Batched via blockIdx.z with element strides.
template <bool B_IS_NT, bool TANH>
__global__ __launch_bounds__(256) void gemm_kernel(
    const float* __restrict__ A, const float* __restrict__ Bm,
    float* __restrict__ C, int M, int N, int K, long lda, long ldb, long ldc,
    long strideA, long strideB, long strideC) {
  __shared__ float As[BK][BM + 4];
  __shared__ float Bs[BK][BN + 4];

  const int bz = blockIdx.z;
  A += (long)bz * strideA;
  Bm += (long)bz * strideB;
  C += (long)bz * strideC;

  const int m0 = blockIdx.y * BM;
  const int n0 = blockIdx.x * BN;
  const int tid = threadIdx.x;
  const int tx = tid & 15;   // 0..15 -> N
  const int ty = tid >> 4;   // 0..15 -> M

  // A-tile loader mapping: 64 rows x 16 k, 4 consecutive k per thread
  const int arow = tid >> 2;        // 0..63
  const int akq = (tid & 3) * 4;    // 0,4,8,12

  float acc[4][4] = {};

  for (int k0 = 0; k0 < K; k0 += BK) {
    float4 av = *(const float4*)(A + (long)(m0 + arow) * lda + k0 + akq);
    As[akq + 0][arow] = av.x;
    As[akq + 1][arow] = av.y;
    As[akq + 2][arow] = av.z;
    As[akq + 3][arow] = av.w;
    if (B_IS_NT) {
      float4 bv = *(const float4*)(Bm + (long)(n0 + arow) * ldb + k0 + akq);
      Bs[akq + 0][arow] = bv.x;
      Bs[akq + 1][arow] = bv.y;
      Bs[akq + 2][arow] = bv.z;
      Bs[akq + 3][arow] = bv.w;
    } else {
      const int brow = tid >> 4;       // 0..15 -> k
      const int bcol = (tid & 15) * 4; // 0..60 -> n
      float4 bv = *(const float4*)(Bm + (long)(k0 + brow) * ldb + n0 + bcol);
      *(float4*)&Bs[brow][bcol] = bv;
    }
    __syncthreads();
#pragma unroll
    for (int kk = 0; kk < BK; ++kk) {
      float4 a4 = *(const float4*)&As[kk][ty * 4];
      float4 b4 = *(const float4*)&Bs[kk][tx * 4];
      float ar[4] = {a4.x, a4.y, a4.z, a4.w};
      float br[4] = {b4.x, b4.y, b4.z, b4.w};
#pragma unroll
      for (int i = 0; i < 4; ++i)
#pragma unroll
        for (int j = 0; j < 4; ++j) acc[i][j] = fmaf(ar[i], br[j], acc[i][j]);
    }
    __syncthreads();
  }

#pragma unroll
  for (int i = 0; i < 4; ++i) {
    float4 o;
    o.x = acc[i][0];
    o.y = acc[i][1];
    o.z = acc[i][2];
    o.w = acc[i][3];
    if (TANH) {
      o.x = tanhf(o.x);
      o.y = tanhf(o.y);
      o.z = tanhf(o.z);
      o.w = tanhf(o.w);
    }
    *(float4*)(C + (long)(m0 + ty * 4 + i) * ldc + n0 + tx * 4) = o;
  }
}

// In-place softmax over rows of length 1024 (rows contiguous).
__global__ __launch_bounds__(256) void softmax_kernel(float* __restrict__ data) {
  float* row = data + (long)blockIdx.x * SLEN;
  const int tid = threadIdx.x;
  float4 v = ((float4*)row)[tid];
  float m = fmaxf(fmaxf(v.x, v.y), fmaxf(v.z, v.w));
#pragma unroll
  for (int off = 32; off > 0; off >>= 1) m = fmaxf(m, __shfl_xor(m, off));
  __shared__ float redm[4];
  __shared__ float reds[4];
  if ((tid & 63) == 0) redm[tid >> 6] = m;
  __syncthreads();
  m = fmaxf(fmaxf(redm[0], redm[1]), fmaxf(redm[2], redm[3]));
  v.x = expf(v.x - m);
  v.y = expf(v.y - m);
  v.z = expf(v.z - m);
  v.w = expf(v.w - m);
  float s = v.x + v.y + v.z + v.w;
#pragma unroll
  for (int off = 32; off > 0; off >>= 1) s += __shfl_xor(s, off);
  if ((tid & 63) == 0) reds[tid >> 6] = s;
  __syncthreads();
  s = reds[0] + reds[1] + reds[2] + reds[3];
  const float inv = 1.0f / s;
  v.x *= inv;
  v.y *= inv;
  v.z *= inv;
  v.w *= inv;
  ((float4*)row)[tid] = v;
}

// concat_c[t, b, DIM + d] = input[b, t, d]
__global__ __launch_bounds__(256) void concat_copy_kernel(
    const float* __restrict__ in, float* __restrict__ concat) {
  const int bt = blockIdx.x;          // b*T + t
  const int b = bt >> 9;              // T = 512
  const int t = bt & 511;
  const float4 v = ((const float4*)(in + (long)bt * DIM))[threadIdx.x];
  ((float4*)(concat + ((long)t * BATCH + b) * (2 * DIM) + DIM))[threadIdx.x] = v;
}

extern "C" void kernel_launch(void* const* d_in, const int* in_sizes, int n_in,
                              void* d_out, int out_size, void* d_ws,
                              size_t ws_size, hipStream_t stream) {
  const float* input = (const float*)d_in[0];    // [B,T,D]
  const float* context = (const float*)d_in[1];  // [B,S,D]
  const float* W_in = (const float*)d_in[2];     // [D,D]
  const float* W_out = (const float*)d_in[3];    // [D,2D]

  float* out = (float*)d_out;
  float* attn_h = out;                                      // [T,B,D]
  float* align = out + (long)TLEN * BATCH * DIM;            // [T,B,S]
  float* concat = align + (long)TLEN * BATCH * SLEN;        // [T,B,2D]

  // h_t scratch lives in the attn_h output region ([B,T,D] layout, 16.7M
  // floats == region size); it's dead before GEMM4 overwrites the region.
  float* h_t = attn_h;

  const long BT = (long)BATCH * TLEN;  // 16384

  // GEMM1: h_t[bt, e] = sum_d input[bt, d] * W_in[e, d]   (NT)
  {
    dim3 grid(DIM / BN, BT / BM, 1);
    gemm_kernel<true, false><<<grid, 256, 0, stream>>>(
        input, W_in, h_t, (int)BT, DIM, DIM, DIM, DIM, DIM, 0, 0, 0);
  }
  // GEMM2 (batched): align[t, b, s] = sum_d h_t[b, t, d] * context[b, s, d]
  {
    dim3 grid(SLEN / BN, TLEN / BM, BATCH);
    gemm_kernel<true, false><<<grid, 256, 0, stream>>>(
        h_t, context, align, TLEN, SLEN, DIM,
        /*lda=*/DIM, /*ldb=*/DIM, /*ldc=*/(long)BATCH * SLEN,
        /*sA=*/(long)TLEN * DIM, /*sB=*/(long)SLEN * DIM, /*sC=*/SLEN);
  }
  // softmax over S for each of T*B rows (rows contiguous in [T,B,S])
  softmax_kernel<<<(int)BT, 256, 0, stream>>>(align);

  // GEMM3 (batched, NN): c[t, b, d] = sum_s P[t, b, s] * context[b, s, d]
  {
    dim3 grid(DIM / BN, TLEN / BM, BATCH);
    gemm_kernel<false, false><<<grid, 256, 0, stream>>>(
        align, context, concat, TLEN, DIM, SLEN,
        /*lda=*/(long)BATCH * SLEN, /*ldb=*/DIM, /*ldc=*/(long)BATCH * 2 * DIM,
        /*sA=*/SLEN, /*sB=*/(long)SLEN * DIM, /*sC=*/2 * DIM);
  }
  // concat_c[t, b, D:2D] = input[b, t, :]
  concat_copy_kernel<<<(int)BT, 256, 0, stream>>>(input, concat);

  // GEMM4: attn_h[tb, d] = tanh( sum_f concat[tb, f] * W_out[d, f] )  (NT)
  {
    dim3 grid(DIM / BN, BT / BM, 1);
    gemm_kernel<true, true><<<grid, 256, 0, stream>>>(
        concat, W_out, attn_h, (int)BT, DIM, 2 * DIM,
        2 * DIM, 2 * DIM, DIM, 0, 0, 0);
  }
}

// Round 2
// 898.060 us; speedup vs baseline: 2.8033x; 2.8033x over previous
//
#include <hip/hip_runtime.h>
#include <cmath>

// Problem constants: B=32, T=512, S=1024, D=1024
#define BATCH 32
#define TLEN  512
#define SLEN  1024
#define DIM   1024

#define BM 128
#define BN 128
#define BK 32

typedef _Float16 h8 __attribute__((ext_vector_type(8)));
typedef _Float16 h4 __attribute__((ext_vector_type(4)));
typedef float f4 __attribute__((ext_vector_type(4)));

#define AS_LD 40   // BK + 8 pad halfs: rows 80B (16B-aligned), frag reads <=2-way
#define B2_LD 134  // BN + 6 pad halfs: 67-word odd stride -> conflict-free b16 reads

// fp16-MFMA GEMM, fp32 in/out, convert-at-staging.
// B_IS_NT=true : C[m,n] = sum_k A[m,k]*B[n,k]  (B rows k-contiguous)
// B_IS_NT=false: C[m,n] = sum_k A[m,k]*B[k,n]  (B rows n-contiguous)
template <bool B_IS_NT, bool TANH>
__global__ __launch_bounds__(256) void gemm_f16(
    const float* __restrict__ A, const float* __restrict__ Bm,
    float* __restrict__ C, int M, int N, int K, long lda, long ldb, long ldc,
    long strideA, long strideB, long strideC) {
  __shared__ _Float16 As[BM * AS_LD];          // 10240 B
  __shared__ _Float16 Bs[BM * AS_LD];          // max(NT 128*40, NN 32*134) halfs

  const int bz = blockIdx.z;
  A += (long)bz * strideA;
  Bm += (long)bz * strideB;
  C += (long)bz * strideC;

  const int m0 = blockIdx.y * BM;
  const int n0 = blockIdx.x * BN;
  const int tid = threadIdx.x;
  const int lane = tid & 63;
  const int wave = tid >> 6;
  const int wm = (wave >> 1) * 64;  // wave m-offset in tile
  const int wn = (wave & 1) * 64;   // wave n-offset in tile
  const int q = lane >> 4;          // quad 0..3
  const int r = lane & 15;          // row/col within 16

  f4 acc[4][4];
#pragma unroll
  for (int i = 0; i < 4; ++i)
#pragma unroll
    for (int j = 0; j < 4; ++j) acc[i][j] = (f4){0.f, 0.f, 0.f, 0.f};

  const int srow = tid >> 3;        // 0..31  (A staging row step)
  const int skq = (tid & 7) * 4;    // 0..28  (A staging k quad)
  const int nrow = tid >> 5;        // 0..7   (NN B staging k row step)
  const int nnq = (tid & 31) * 4;   // 0..124 (NN B staging n quad)

  for (int k0 = 0; k0 < K; k0 += BK) {
    // ---- stage A tile [BM x BK] fp32 -> fp16 LDS ----
#pragma unroll
    for (int it = 0; it < 4; ++it) {
      const int row = it * 32 + srow;
      f4 v = *(const f4*)(A + (long)(m0 + row) * lda + k0 + skq);
      h4 hv = {(_Float16)v.x, (_Float16)v.y, (_Float16)v.z, (_Float16)v.w};
      *(h4*)&As[row * AS_LD + skq] = hv;
    }
    // ---- stage B tile ----
    if (B_IS_NT) {
#pragma unroll
      for (int it = 0; it < 4; ++it) {
        const int row = it * 32 + srow;
        f4 v = *(const f4*)(Bm + (long)(n0 + row) * ldb + k0 + skq);
        h4 hv = {(_Float16)v.x, (_Float16)v.y, (_Float16)v.z, (_Float16)v.w};
        *(h4*)&Bs[row * AS_LD + skq] = hv;
      }
    } else {
      // B is [K x N]; stage as [k][n] rows, odd-word stride
#pragma unroll
      for (int it = 0; it < 4; ++it) {
        const int krow = it * 8 + nrow;
        f4 v = *(const f4*)(Bm + (long)(k0 + krow) * ldb + n0 + nnq);
        _Float16* p = &Bs[krow * B2_LD + nnq];
        // 4B-aligned only (odd word stride) -> two half2 stores
        *(__attribute__((ext_vector_type(2))) _Float16*)p =
            (__attribute__((ext_vector_type(2))) _Float16){(_Float16)v.x, (_Float16)v.y};
        *(__attribute__((ext_vector_type(2))) _Float16*)(p + 2) =
            (__attribute__((ext_vector_type(2))) _Float16){(_Float16)v.z, (_Float16)v.w};
      }
    }
    __syncthreads();

    // ---- fragments + MFMA ----
    h8 av[4], bv[4];
#pragma unroll
    for (int mt = 0; mt < 4; ++mt)
      av[mt] = *(const h8*)&As[(wm + mt * 16 + r) * AS_LD + q * 8];
    if (B_IS_NT) {
#pragma unroll
      for (int nt = 0; nt < 4; ++nt)
        bv[nt] = *(const h8*)&Bs[(wn + nt * 16 + r) * AS_LD + q * 8];
    } else {
#pragma unroll
      for (int nt = 0; nt < 4; ++nt) {
        h8 t;
#pragma unroll
        for (int j = 0; j < 8; ++j)
          t[j] = Bs[(q * 8 + j) * B2_LD + wn + nt * 16 + r];
        bv[nt] = t;
      }
    }
#pragma unroll
    for (int mt = 0; mt < 4; ++mt)
#pragma unroll
      for (int nt = 0; nt < 4; ++nt)
        acc[mt][nt] = __builtin_amdgcn_mfma_f32_16x16x32_f16(
            av[mt], bv[nt], acc[mt][nt], 0, 0, 0);
    __syncthreads();
  }

  // ---- epilogue: D[row=(q*4+i)][col=r] per 16x16 tile ----
#pragma unroll
  for (int mt = 0; mt < 4; ++mt) {
#pragma unroll
    for (int nt = 0; nt < 4; ++nt) {
#pragma unroll
      for (int i = 0; i < 4; ++i) {
        float x = acc[mt][nt][i];
        if (TANH) x = tanhf(x);
        C[(long)(m0 + wm + mt * 16 + q * 4 + i) * ldc + n0 + wn + nt * 16 + r] = x;
      }
    }
  }
}

// In-place softmax over rows of length 1024 (rows contiguous).
__global__ __launch_bounds__(256) void softmax_kernel(float* __restrict__ data) {
  float* row = data + (long)blockIdx.x * SLEN;
  const int tid = threadIdx.x;
  float4 v = ((float4*)row)[tid];
  float m = fmaxf(fmaxf(v.x, v.y), fmaxf(v.z, v.w));
#pragma unroll
  for (int off = 32; off > 0; off >>= 1) m = fmaxf(m, __shfl_xor(m, off));
  __shared__ float redm[4];
  __shared__ float reds[4];
  if ((tid & 63) == 0) redm[tid >> 6] = m;
  __syncthreads();
  m = fmaxf(fmaxf(redm[0], redm[1]), fmaxf(redm[2], redm[3]));
  v.x = expf(v.x - m);
  v.y = expf(v.y - m);
  v.z = expf(v.z - m);
  v.w = expf(v.w - m);
  float s = v.x + v.y + v.z + v.w;
#pragma unroll
  for (int off = 32; off > 0; off >>= 1) s += __shfl_xor(s, off);
  if ((tid & 63) == 0) reds[tid >> 6] = s;
  __syncthreads();
  s = reds[0] + reds[1] + reds[2] + reds[3];
  const float inv = 1.0f / s;
  v.x *= inv;
  v.y *= inv;
  v.z *= inv;
  v.w *= inv;
  ((float4*)row)[tid] = v;
}

// concat_c[t, b, DIM + d] = input[b, t, d]
__global__ __launch_bounds__(256) void concat_copy_kernel(
    const float* __restrict__ in, float* __restrict__ concat) {
  const int bt = blockIdx.x;  // b*T + t
  const int b = bt >> 9;      // T = 512
  const int t = bt & 511;
  const float4 v = ((const float4*)(in + (long)bt * DIM))[threadIdx.x];
  ((float4*)(concat + ((long)t * BATCH + b) * (2 * DIM) + DIM))[threadIdx.x] = v;
}

extern "C" void kernel_launch(void* const* d_in, const int* in_sizes, int n_in,
                              void* d_out, int out_size, void* d_ws,
                              size_t ws_size, hipStream_t stream) {
  const float* input = (const float*)d_in[0];    // [B,T,D]
  const float* context = (const float*)d_in[1];  // [B,S,D]
  const float* W_in = (const float*)d_in[2];     // [D,D]
  const float* W_out = (const float*)d_in[3];    // [D,2D]

  float* out = (float*)d_out;
  float* attn_h = out;                                // [T,B,D]
  float* align = out + (long)TLEN * BATCH * DIM;      // [T,B,S]
  float* concat = align + (long)TLEN * BATCH * SLEN;  // [T,B,2D]

  // h_t scratch lives in the attn_h output region ([B,T,D], same element
  // count); fully consumed by GEMM2 before GEMM4 overwrites the region.
  float* h_t = attn_h;

  const long BT = (long)BATCH * TLEN;  // 16384

  // GEMM1 (NT): h_t[bt, e] = sum_d input[bt, d] * W_in[e, d]
  {
    dim3 grid(DIM / BN, BT / BM, 1);
    gemm_f16<true, false><<<grid, 256, 0, stream>>>(
        input, W_in, h_t, (int)BT, DIM, DIM, DIM, DIM, DIM, 0, 0, 0);
  }
  // GEMM2 (NT, batched): align[t, b, s] = sum_d h_t[b, t, d] * ctx[b, s, d]
  {
    dim3 grid(SLEN / BN, TLEN / BM, BATCH);
    gemm_f16<true, false><<<grid, 256, 0, stream>>>(
        h_t, context, align, TLEN, SLEN, DIM,
        /*lda=*/DIM, /*ldb=*/DIM, /*ldc=*/(long)BATCH * SLEN,
        /*sA=*/(long)TLEN * DIM, /*sB=*/(long)SLEN * DIM, /*sC=*/SLEN);
  }
  softmax_kernel<<<(int)BT, 256, 0, stream>>>(align);

  // GEMM3 (NN, batched): c[t, b, d] = sum_s P[t, b, s] * ctx[b, s, d]
  {
    dim3 grid(DIM / BN, TLEN / BM, BATCH);
    gemm_f16<false, false><<<grid, 256, 0, stream>>>(
        align, context, concat, TLEN, DIM, SLEN,
        /*lda=*/(long)BATCH * SLEN, /*ldb=*/DIM, /*ldc=*/(long)BATCH * 2 * DIM,
        /*sA=*/SLEN, /*sB=*/(long)SLEN * DIM, /*sC=*/2 * DIM);
  }
  concat_copy_kernel<<<(int)BT, 256, 0, stream>>>(input, concat);

  // GEMM4 (NT + tanh): attn_h[tb, d] = tanh(sum_f concat[tb, f] * W_out[d, f])
  {
    dim3 grid(DIM / BN, BT / BM, 1);
    gemm_f16<true, true><<<grid, 256, 0, stream>>>(
        concat, W_out, attn_h, (int)BT, DIM, 2 * DIM,
        2 * DIM, 2 * DIM, DIM, 0, 0, 0);
  }
}